// Round 1
// baseline (535.546 us; speedup 1.0000x reference)
//
#include <hip/hip_runtime.h>
#include <hip/hip_bf16.h>

// Fused 24-step LSTM forecaster, MI355X gfx950 — round 1 rework.
// Key changes vs previous version:
//  * fc_in folded into the gate GEMM (no nonlinearity between them):
//      gates = z @ Wcat^T,  z = [xn(24) | feat(17) | 1@k41 | pad | h(32)], K=96
//    Bias enters via the constant-1 column; all gate weights pre-scaled by
//    log2(e) so activations use native exp2 (v_exp_f32) with no input mul.
//  * xn sliding window register-resident (A-frag octets), slid with alignbit
//    + 1 shfl per step; feat loaded straight into frags (1-step prefetch).
//    No Xs/buf staging LDS at all; only the h D->A transpose uses LDS.
//  * ka weights in regs (32 VGPR); kb/kc weight frags streamed from a
//    block-shared 16KB LDS copy (conflict-free ds_read_b128, not hoistable).
//  * __launch_bounds__(256,4) -> <=128 VGPR, 4 waves/SIMD target.

#define BN     512
#define HISTN  24
#define CNN    184
#define FN     17
#define PREDN  24
#define HIDN   32
#define INN    41
#define CELLS  (BN * CNN)          // 94208 cells, 64 per block -> 1472 blocks
#define FROW   (CNN * FN)          // 3128 floats per (b,t) feature row
#define PMROW  (HISTN * CNN)       // 4416 floats per b in pm25
#define LOG2E  1.4426950408889634f

typedef __attribute__((ext_vector_type(8))) short  short8;
typedef __attribute__((ext_vector_type(4))) float  float4v;
typedef __attribute__((ext_vector_type(4))) int    int4v;

#define MFMA_B16(a, b, c) __builtin_amdgcn_mfma_f32_16x16x32_bf16(a, b, c, 0, 0, 0)

__device__ __forceinline__ short f2bf(float f) {
  union { float f; unsigned u; } v; v.f = f;
  unsigned r = v.u + 0x7fffu + ((v.u >> 16) & 1u);   // RNE
  return (short)(r >> 16);
}
__device__ __forceinline__ int pack2(short lo, short hi) {
  return (int)(((unsigned)(unsigned short)lo) | (((unsigned)(unsigned short)hi) << 16));
}
// y is pre-scaled by log2(e) (folded into the weights)
__device__ __forceinline__ float sig_s(float y) {
  return __builtin_amdgcn_rcpf(1.0f + exp2f(-y));
}
__device__ __forceinline__ float tanh_s(float y) {
  const float e = exp2f(y + y);
  return 1.0f - 2.0f * __builtin_amdgcn_rcpf(1.0f + e);
}
__device__ __forceinline__ float tanh_u(float x) {   // unscaled input (c state)
  const float e = exp2f(x * (2.0f * LOG2E));
  return 1.0f - 2.0f * __builtin_amdgcn_rcpf(1.0f + e);
}

// ---------------------------------------------------------------------------
// Setup kernel: build folded gate weights, bf16, in MFMA B-frag order.
//   Wcat[g][k]: k<41  : sum_m W_ih[g][m]*W_in[m][k]
//               k==41 : b_ih[g]+b_hh[g]+sum_m W_ih[g][m]*b_in[m]  (bias col)
//               64<=k : W_hh[g][k-64]          (else 0)
//   all * log2(e).  Frag elem index: ((f*8+nt)*64 + q*16 + c0)*8 + j
//   with f=k>>5, q=(k>>3)&3, j=k&7, nt=g>>4, c0=g&15.
__global__ void build_weights(const float* __restrict__ W_in, const float* __restrict__ b_in,
                              const float* __restrict__ W_ih, const float* __restrict__ W_hh,
                              const float* __restrict__ b_ih, const float* __restrict__ b_hh,
                              short* __restrict__ wfrag)
{
  const int tid = blockIdx.x * 256 + threadIdx.x;
  if (tid >= 128 * 12) return;
  const int g  = tid / 12;         // gate row 0..127
  const int kg = tid % 12;         // k-octet 0..11
  const int k0 = kg * 8;

  float v[8];
  #pragma unroll
  for (int j = 0; j < 8; ++j) v[j] = 0.f;

  if (k0 < INN) {                  // folded fc_in region
    for (int m = 0; m < HIDN; ++m) {
      const float wih = W_ih[g * HIDN + m];
      #pragma unroll
      for (int j = 0; j < 8; ++j) {
        const int k = k0 + j;
        if (k < INN) v[j] += wih * W_in[m * INN + k];
      }
    }
  }
  if (k0 <= INN && INN < k0 + 8) { // bias column k = 41
    float bv = b_ih[g] + b_hh[g];
    for (int m = 0; m < HIDN; ++m) bv += W_ih[g * HIDN + m] * b_in[m];
    v[INN - k0] = bv;
  }
  if (k0 >= 64) {                  // W_hh region
    #pragma unroll
    for (int j = 0; j < 8; ++j) v[j] = W_hh[g * HIDN + (k0 + j - 64)];
  }

  const int f = kg >> 2, q = kg & 3, nt = g >> 4, c0 = g & 15;
  short* dst = wfrag + (((f * 8 + nt) * 64 + q * 16 + c0) * 8);
  #pragma unroll
  for (int j = 0; j < 8; ++j) dst[j] = f2bf(v[j] * LOG2E);
}

// ---------------------------------------------------------------------------
__global__ __launch_bounds__(256, 4)
void lstm_fused(const float* __restrict__ pm25,
                const float* __restrict__ feat,
                const short* __restrict__ wfrag,
                const float* __restrict__ W_out, const float* __restrict__ b_out,
                float* __restrict__ out)
{
  __shared__ __align__(16) short wlds[2 * 8 * 64 * 8];   // kb,kc weight frags: 16 KB
  __shared__ __align__(16) short hlds[4][16][40];        // per-wave h tile, padded: 5 KB

  const int tid   = threadIdx.x;
  const int w     = tid >> 6;
  const int lane  = tid & 63;
  const int q     = lane >> 4;       // k-octet role 0..3
  const int c0    = lane & 15;       // A-frag row / B-frag col
  const int cell0 = blockIdx.x << 6;
  const int mycell = cell0 + (w << 4) + c0;   // cell of this lane's A-row

  // ---- stage kb/kc weight frags to LDS (16384 B, coalesced) ----
  {
    const int4v* src = (const int4v*)(wfrag + 8 * 64 * 8);   // skip ka frag
    int4v* dst = (int4v*)wlds;
    #pragma unroll
    for (int i = 0; i < 4; ++i) dst[tid + 256 * i] = src[tid + 256 * i];
  }

  // ---- ka weights (window+feat[0:8] columns) into registers ----
  short8 Wka[8];
  #pragma unroll
  for (int nt = 0; nt < 8; ++nt)
    Wka[nt] = *(const short8*)(wfrag + (nt * 64 + lane) * 8);

  float woutr[2];
  woutr[0] = W_out[c0]; woutr[1] = W_out[16 + c0];
  const float bo = b_out[0];

  // ---- zero this wave's h tile (h0 = 0) ----
  {
    short* hz = &hlds[w][0][0];
    for (int i = lane; i < 16 * 40; i += 64) hz[i] = 0;
  }

  // ---- per-lane cell addressing ----
  const int bb = mycell / CNN, cc = mycell % CNN;

  // register-resident xn window: lane (q<3) holds X[k = q*8 .. q*8+7]
  int wv[4] = {0, 0, 0, 0};
  if (q < 3) {
    const float* src = pm25 + bb * PMROW + cc * HISTN + (q << 3);
    short tmp[8];
    #pragma unroll
    for (int j = 0; j < 8; ++j) tmp[j] = f2bf(src[j]);
    #pragma unroll
    for (int i = 0; i < 4; ++i) wv[i] = pack2(tmp[2 * i], tmp[2 * i + 1]);
  }

  // feat prefetch roles: q3 -> feat[0:8] (ka), q0 -> feat[8:16] (kb),
  // q1 -> feat[16] (kb elem0), q2 -> none
  const int pfo = (q == 3) ? 0 : (q == 0) ? 8 : 16;
  const float* fptr = feat + (size_t)(bb * 48 + HISTN) * FROW + cc * FN + pfo;
  float pf[8] = {0.f, 0.f, 0.f, 0.f, 0.f, 0.f, 0.f, 0.f};
  if (q != 2) {
    if (q == 1) pf[0] = fptr[0];
    else {
      #pragma unroll
      for (int i = 0; i < 8; ++i) pf[i] = fptr[i];
    }
  }

  // output addressing for the 4 D-rows this lane covers (c0==0 stores)
  int obase[4];
  #pragma unroll
  for (int r = 0; r < 4; ++r) {
    const int cgr = cell0 + (w << 4) + (q << 2) + r;
    obase[r] = (cgr / CNN) * (PREDN * CNN) + (cgr % CNN);
  }

  float cst[2][4] = {{0.f, 0.f, 0.f, 0.f}, {0.f, 0.f, 0.f, 0.f}};

  __syncthreads();   // wlds staged

  const char* wl = (const char*)wlds;
  int wbase = lane * 16;                       // byte offset for weight reads
  const short* hrd = &hlds[w][c0][q << 3];     // kc A-frag source
  short* hw = &hlds[w][0][0];

  union WU { int i[4]; short8 v8; };

  #pragma unroll 1
  for (int t = 0; t < PREDN; ++t) {
    asm volatile("" : "+v"(wbase));   // keep per-step LDS weight reads in-loop

    // ---- build A-frags ----
    WU au;
    au.i[0] = wv[0]; au.i[1] = wv[1]; au.i[2] = wv[2]; au.i[3] = wv[3];
    if (q == 3) {
      #pragma unroll
      for (int i = 0; i < 4; ++i) au.i[i] = pack2(f2bf(pf[2 * i]), f2bf(pf[2 * i + 1]));
    }
    const short8 ka = au.v8;

    WU bu;
    bu.i[0] = 0; bu.i[1] = 0; bu.i[2] = 0; bu.i[3] = 0;
    if (q == 0) {
      #pragma unroll
      for (int i = 0; i < 4; ++i) bu.i[i] = pack2(f2bf(pf[2 * i]), f2bf(pf[2 * i + 1]));
    } else if (q == 1) {
      bu.i[0] = pack2(f2bf(pf[0]), (short)0x3f80);   // [feat16 | 1.0] bias col
    }
    const short8 kb = bu.v8;

    const short8 kc = *(const short8*)hrd;           // h_{t-1}, A-layout

    // ---- prefetch next-step features ----
    if (t < PREDN - 1 && q != 2) {
      fptr += FROW;
      if (q == 1) pf[0] = fptr[0];
      else {
        #pragma unroll
        for (int i = 0; i < 8; ++i) pf[i] = fptr[i];
      }
    }

    // ---- single gate GEMM, K=96 ----
    __builtin_amdgcn_s_setprio(1);
    const float4v z4 = {0.f, 0.f, 0.f, 0.f};
    float4v acc[8];
    #pragma unroll
    for (int nt = 0; nt < 8; ++nt) {
      float4v a = MFMA_B16(ka, Wka[nt], z4);
      const short8 wkb = *(const short8*)(wl + wbase + nt * 1024);
      a = MFMA_B16(kb, wkb, a);
      const short8 wkc = *(const short8*)(wl + wbase + 8192 + nt * 1024);
      a = MFMA_B16(kc, wkc, a);
      acc[nt] = a;
    }
    __builtin_amdgcn_s_setprio(0);

    // ---- epilogue: activations, state, h -> LDS, pred partials ----
    float part[4] = {0.f, 0.f, 0.f, 0.f};
    #pragma unroll
    for (int s = 0; s < 2; ++s) {
      #pragma unroll
      for (int r = 0; r < 4; ++r) {
        const float iv = sig_s(acc[0 + s][r]);
        const float fv = sig_s(acc[2 + s][r]);
        const float gv = tanh_s(acc[4 + s][r]);
        const float ov = sig_s(acc[6 + s][r]);
        const float cn = fv * cst[s][r] + iv * gv;
        cst[s][r] = cn;
        const float hv = ov * tanh_u(cn);
        hw[((q << 2) + r) * 40 + (s << 4) + c0] = f2bf(hv);
        part[r] += woutr[s] * hv;
      }
    }

    // ---- reduce pred over the 16 lanes of this q-group ----
    #pragma unroll
    for (int r = 0; r < 4; ++r) {
      float p = part[r];
      p += __shfl_xor(p, 1);
      p += __shfl_xor(p, 2);
      p += __shfl_xor(p, 4);
      p += __shfl_xor(p, 8);
      part[r] = p;
    }
    if (c0 == 0) {
      #pragma unroll
      for (int r = 0; r < 4; ++r)
        out[obase[r] + t * CNN] = part[r] + bo;
    }

    // ---- broadcast pred to window-insert lanes, slide the window ----
    if (t < PREDN - 1) {
      const float v01 = (c0 & 1) ? part[1] : part[0];
      const float v23 = (c0 & 1) ? part[3] : part[2];
      const float vs  = (c0 & 2) ? v23 : v01;
      // source lane (c0>>2)*16 + c0 holds pred(row c0) in its selected slot
      const float pv = __shfl(vs, ((c0 >> 2) << 4) | c0) + bo;
      const int pw = (int)(unsigned short)f2bf(pv);
      const int nb = __shfl(wv[0], (lane + 16) & 63);  // next octet's elem0
      const int inc = (q == 2) ? pw : nb;
      wv[0] = (int)(((unsigned)wv[0] >> 16) | ((unsigned)wv[1] << 16));
      wv[1] = (int)(((unsigned)wv[1] >> 16) | ((unsigned)wv[2] << 16));
      wv[2] = (int)(((unsigned)wv[2] >> 16) | ((unsigned)wv[3] << 16));
      wv[3] = (int)(((unsigned)wv[3] >> 16) | ((unsigned)inc   << 16));
    }
  }
}

extern "C" void kernel_launch(void* const* d_in, const int* in_sizes, int n_in,
                              void* d_out, int out_size, void* d_ws, size_t ws_size,
                              hipStream_t stream) {
  (void)in_sizes; (void)n_in; (void)out_size; (void)ws_size;
  const float* pm25  = (const float*)d_in[0];
  const float* feat  = (const float*)d_in[1];
  // d_in[2] = time_feature, unused by the reference
  const float* W_in  = (const float*)d_in[3];
  const float* b_in  = (const float*)d_in[4];
  const float* W_ih  = (const float*)d_in[5];
  const float* W_hh  = (const float*)d_in[6];
  const float* b_ih  = (const float*)d_in[7];
  const float* b_hh  = (const float*)d_in[8];
  const float* W_out = (const float*)d_in[9];
  const float* b_out = (const float*)d_in[10];
  float* out = (float*)d_out;

  short* wfrag = (short*)d_ws;   // 24 octet-groups * 64 lanes * 8 bf16 = 24576 B

  build_weights<<<dim3(6), dim3(256), 0, stream>>>(
      W_in, b_in, W_ih, W_hh, b_ih, b_hh, wfrag);
  lstm_fused<<<dim3(CELLS / 64), dim3(256), 0, stream>>>(
      pm25, feat, wfrag, W_out, b_out, out);
}